// Round 2
// baseline (1806.370 us; speedup 1.0000x reference)
//
#include <hip/hip_runtime.h>

// S=8, N=4096, F_IN=F_OUT=128
constexpr int N  = 4096;
constexpr int F  = 128;
constexpr int S  = 8;
constexpr int BM = 16;        // rows per workgroup
constexpr int BK = 64;        // k-chunk
constexpr int NC = N / BK;    // 64 chunks
constexpr int NT = 512;       // threads per block (8 waves)

typedef float f4 __attribute__((ext_vector_type(4)));

// Barrier that waits only on LDS ops (lgkmcnt), leaving global loads
// (vmcnt) in flight across the barrier.
__device__ __forceinline__ void bar_sync() {
  asm volatile("s_waitcnt lgkmcnt(0)" ::: "memory");
  __builtin_amdgcn_s_barrier();
  asm volatile("" ::: "memory");
}

__global__ __launch_bounds__(NT, 1) void ggd_fused(
    const float* __restrict__ theta,
    const float* __restrict__ Ts,     // [S][N][N]
    const float* __restrict__ x,      // [N][F]
    const float* __restrict__ a,      // [N][N]
    const float* __restrict__ W,      // [F][F]  row-major [fo][fi]
    const float* __restrict__ bfc,    // [F]
    const float* __restrict__ alpha,  // [F]
    float* __restrict__ out)          // [N][F]
{
  __shared__ float q_lds[2][BM][BK];   // 8 KB double-buffered
  __shared__ float x_lds[2][BK * F];   // 64 KB double-buffered
  __shared__ float p_lds[BM][F];       // 8 KB epilogue staging

  const int t    = threadIdx.x;
  const int n0   = blockIdx.x * BM;
  const int wave = t >> 6;
  const int lane = t & 63;
  const bool qrole = (wave < 4);       // waves 0-3: T/a -> q; waves 4-7: x tile

  // theta -> registers (uniform)
  float th[S];
#pragma unroll
  for (int s = 0; s < S; ++s) th[s] = theta[s];

  // ---- producer mapping (threads 0..255): row qr, cols [qk, qk+4) ----
  const int qr = t >> 4;               // 0..15 (valid when qrole)
  const int qk = (t & 15) << 2;
  const size_t rowOff  = (size_t)(n0 + qr) * N;
  const size_t sliceSz = (size_t)N * N;

  // ---- x-stager mapping (threads 256..511): 8 f4 slots each ----
  const int ts = t - 256;              // 0..255 (valid when !qrole)

  // ---- FMA mapping (all 512 threads): wave w -> rows {2w,2w+1} ----
  const int frow = 2 * wave + (lane >> 5);   // 0..15
  const int fcol = lane & 31;                // feature group, feats fcol*4..+4

  f4 acc = (f4)(0.f);

  // staging registers
  f4 tv[S];
  f4 av;
  f4 xs[8];

  auto prefetch = [&](int c) {
    if (qrole) {
      const size_t off = rowOff + (size_t)c * BK + qk;
      av = *(const f4*)(a + off);
#pragma unroll
      for (int s = 0; s < S; ++s)
        tv[s] = *(const f4*)(Ts + (size_t)s * sliceSz + off);
    } else {
      const float* xg = x + (size_t)c * BK * F;
#pragma unroll
      for (int i = 0; i < 8; ++i)
        xs[i] = *(const f4*)(xg + (size_t)(i * 256 + ts) * 4);
    }
  };

  auto commit = [&](int buf) {
    if (qrole) {
      f4 q;
#pragma unroll
      for (int j = 0; j < 4; ++j) {
        float sum = th[0] * tv[0][j];
#pragma unroll
        for (int s = 1; s < S; ++s) sum = fmaf(th[s], tv[s][j], sum);
        q[j] = av[j] * sum;
      }
      *(f4*)&q_lds[buf][qr][qk] = q;
    } else {
      float* xl = &x_lds[buf][0];
#pragma unroll
      for (int i = 0; i < 8; ++i)
        *(f4*)(xl + (i * 256 + ts) * 4) = xs[i];
    }
  };

  // prologue: fill buffer 0
  prefetch(0);
  commit(0);
  bar_sync();

  for (int c = 0; c < NC; ++c) {
    const int buf = c & 1;
    if (c + 1 < NC) prefetch(c + 1);   // HBM/L2 loads fly over the FMA phase

    // ---- compute on chunk c, purely from LDS ----
    const float* qrow = &q_lds[buf][frow][0];
    const float* xcol = &x_lds[buf][0] + fcol * 4;
#pragma unroll
    for (int k4 = 0; k4 < BK / 4; ++k4) {
      f4 qv = *(const f4*)(qrow + k4 * 4);
#pragma unroll
      for (int j = 0; j < 4; ++j) {
        f4 xv = *(const f4*)(xcol + (size_t)(k4 * 4 + j) * F);
#pragma unroll
        for (int e = 0; e < 4; ++e)
          acc[e] = fmaf(qv[j], xv[e], acc[e]);
      }
    }

    if (c + 1 < NC) commit(buf ^ 1);   // vmcnt wait lands here, after FMA
    bar_sync();
  }

  // ---- epilogue ----
  // PReLU over input-feature channels, stage p
  {
    f4 al = *(const f4*)(alpha + fcol * 4);
#pragma unroll
    for (int j = 0; j < 4; ++j)
      acc[j] = acc[j] >= 0.f ? acc[j] : al[j] * acc[j];
    *(f4*)&p_lds[frow][fcol * 4] = acc;
  }

  // stage W transposed into retired x_lds: wt[fi*128 + fo]
  float* wt = &x_lds[0][0];
  {
    const int fo  = t & 127;
    const int fib = (t >> 7) * 32;
    f4 wreg[8];
#pragma unroll
    for (int i = 0; i < 8; ++i)
      wreg[i] = *(const f4*)(W + (size_t)fo * F + fib + i * 4);
#pragma unroll
    for (int i = 0; i < 8; ++i)
#pragma unroll
      for (int jj = 0; jj < 4; ++jj)
        wt[(size_t)(fib + i * 4 + jj) * F + fo] = wreg[i][jj];
  }
  bar_sync();

  // FC: out[n][fo] = b[fo] + sum_fi p[n][fi] * W[fo][fi]
  {
    const int rr  = t >> 5;            // 0..15
    const int fo4 = (t & 31) * 4;
    f4 accF = *(const f4*)(bfc + fo4);
    const float* pr = &p_lds[rr][0];
#pragma unroll
    for (int fi4 = 0; fi4 < F / 4; ++fi4) {
      f4 pv = *(const f4*)(pr + fi4 * 4);
#pragma unroll
      for (int j = 0; j < 4; ++j) {
        f4 wv = *(const f4*)(wt + (size_t)(fi4 * 4 + j) * F + fo4);
#pragma unroll
        for (int e = 0; e < 4; ++e)
          accF[e] = fmaf(pv[j], wv[e], accF[e]);
      }
    }
    *(f4*)(out + (size_t)(n0 + rr) * F + fo4) = accF;
  }
}

extern "C" void kernel_launch(void* const* d_in, const int* in_sizes, int n_in,
                              void* d_out, int out_size, void* d_ws, size_t ws_size,
                              hipStream_t stream) {
  const float* theta = (const float*)d_in[0];
  const float* Ts    = (const float*)d_in[1];
  const float* x     = (const float*)d_in[2];
  const float* a     = (const float*)d_in[3];
  const float* W     = (const float*)d_in[4];
  const float* bfc   = (const float*)d_in[5];
  const float* alpha = (const float*)d_in[6];
  float* out = (float*)d_out;

  ggd_fused<<<dim3(N / BM), dim3(NT), 0, stream>>>(
      theta, Ts, x, a, W, bfc, alpha, out);
}

// Round 4
// 921.514 us; speedup vs baseline: 1.9602x; 1.9602x over previous
//
#include <hip/hip_runtime.h>

// S=8, N=4096, F_IN=F_OUT=128
constexpr int N  = 4096;
constexpr int F  = 128;
constexpr int S  = 8;
constexpr int BM = 64;            // rows per block (kernel1)
constexpr int KSPLIT = 8;
constexpr int KRANGE = N / KSPLIT;  // 512
constexpr int BK = 32;            // k-chunk
constexpr int NCH = KRANGE / BK;  // 16 chunks per block
constexpr int NT = 256;

typedef float f4 __attribute__((ext_vector_type(4)));

// Barrier that waits only on LDS ops; global loads stay in flight unless we
// explicitly drain vmcnt first.
__device__ __forceinline__ void bar_sync() {
  asm volatile("s_waitcnt lgkmcnt(0)" ::: "memory");
  __builtin_amdgcn_s_barrier();
  asm volatile("" ::: "memory");
}

__device__ __forceinline__ void vm_drain() {
  asm volatile("s_waitcnt vmcnt(0)" ::: "memory");
}

// async global->LDS, 16B per lane; LDS dest = wave-uniform base + lane*16.
__device__ __forceinline__ void gload_lds16(const float* g, float* l) {
  __builtin_amdgcn_global_load_lds(
      (const __attribute__((address_space(1))) void*)g,
      (__attribute__((address_space(3))) void*)l, 16, 0, 0);
}

// ---------------- kernel 1: q-gen + q@x partial, k-split ----------------
__global__ __launch_bounds__(NT, 2) void ggd_diffuse(
    const float* __restrict__ theta,
    const float* __restrict__ Ts,     // [S][N][N]
    const float* __restrict__ x,      // [N][F]
    const float* __restrict__ a,      // [N][N]
    float* __restrict__ out)          // [N][F] accumulator (pre-zeroed)
{
  __shared__ float q_lds[2][BM][BK];  // 16 KB, double-buffered, XOR-swizzled
  __shared__ float x_lds[2][BK * F];  // 32 KB, double-buffered, linear

  const int t  = threadIdx.x;
  const int rb = blockIdx.x >> 3;     // 0..63   row block
  const int ks = blockIdx.x & 7;      // 0..7    k-split (maps ~1:1 to XCD)
  const int n0 = rb * BM;
  const int k0 = ks * KRANGE;

  float th[S];
#pragma unroll
  for (int s = 0; s < S; ++s) th[s] = theta[s];

  const int wave = t >> 6, lane = t & 63;

  // producer mapping: row pr (0..63), cols pkb..pkb+7
  const int pr  = t >> 2;
  const int pkb = (t & 3) * 8;
  const int psw = (pr & 7) << 2;      // XOR swizzle for bank spread
  const size_t prowOff = (size_t)(n0 + pr) * N + k0 + pkb;
  const size_t slice   = (size_t)N * N;

  // consumer mapping: rows rg*8..rg*8+7, feats fg*4..fg*4+3
  const int rg = t >> 5;              // 0..7
  const int fg = t & 31;              // 0..31

  f4 acc[8];
#pragma unroll
  for (int r = 0; r < 8; ++r) acc[r] = (f4)(0.f);

  // staging registers for next chunk's T/a (9 arrays x 2 f4 = 72 VGPR)
  f4 sa[2];
  f4 st[S][2];

  auto load_Ta = [&](int c) {
    const size_t off = prowOff + (size_t)c * BK;
#pragma unroll
    for (int h = 0; h < 2; ++h) sa[h] = *(const f4*)(a + off + h * 4);
#pragma unroll
    for (int s = 0; s < S; ++s)
#pragma unroll
      for (int h = 0; h < 2; ++h)
        st[s][h] = *(const f4*)(Ts + (size_t)s * slice + off + h * 4);
  };

  auto commit_q = [&](int buf) {
#pragma unroll
    for (int h = 0; h < 2; ++h) {
      f4 q;
#pragma unroll
      for (int j = 0; j < 4; ++j) {
        float sum = th[0] * st[0][h][j];
#pragma unroll
        for (int s = 1; s < S; ++s) sum = fmaf(th[s], st[s][h][j], sum);
        q[j] = sa[h][j] * sum;
      }
      *(f4*)&q_lds[buf][pr][(pkb + 4 * h) ^ psw] = q;
    }
  };

  auto stage_x = [&](int c, int buf) {
    const float* xg = x + (size_t)(k0 + c * BK) * F;
#pragma unroll
    for (int i = 0; i < 4; ++i) {
      const int seg = (wave * 4 + i) * 256;   // wave-uniform LDS base
      gload_lds16(xg + seg + lane * 4, &x_lds[buf][seg]);
    }
  };

  // prologue
  load_Ta(0);
  stage_x(0, 0);
  commit_q(0);
  vm_drain();
  bar_sync();

  for (int c = 0; c < NCH; ++c) {
    const int buf = c & 1;
    if (c + 1 < NCH) {
      load_Ta(c + 1);             // regs; waited by commit_q below
      stage_x(c + 1, buf ^ 1);    // async LDS; waited by vm_drain below
    }

    // ---- compute chunk c purely from LDS ----
    const float* qb = &q_lds[buf][rg * 8][0];
    const float* xb = &x_lds[buf][0] + fg * 4;
#pragma unroll
    for (int k4 = 0; k4 < BK / 4; ++k4) {
      f4 xv[4];
#pragma unroll
      for (int j = 0; j < 4; ++j)
        xv[j] = *(const f4*)(xb + (size_t)(k4 * 4 + j) * F);
#pragma unroll
      for (int rr = 0; rr < 8; ++rr) {
        f4 qv = *(const f4*)(qb + rr * BK + ((k4 * 4) ^ (rr << 2)));
#pragma unroll
        for (int j = 0; j < 4; ++j)
#pragma unroll
          for (int e = 0; e < 4; ++e)
            acc[rr][e] = fmaf(qv[j], xv[j][e], acc[rr][e]);
      }
    }

    if (c + 1 < NCH) commit_q(buf ^ 1);
    vm_drain();
    bar_sync();
  }

  // accumulate partials (8 k-split blocks per row tile)
#pragma unroll
  for (int rr = 0; rr < 8; ++rr) {
    float* op = out + (size_t)(n0 + rg * 8 + rr) * F + fg * 4;
#pragma unroll
    for (int e = 0; e < 4; ++e) atomicAdd(op + e, acc[rr][e]);
  }
}

// ---------------- kernel 2: PReLU + FC, in-place on out ----------------
__global__ __launch_bounds__(256, 2) void ggd_fc(
    const float* __restrict__ W,      // [F][F] row-major [fo][fi]
    const float* __restrict__ bfc,    // [F]
    const float* __restrict__ alpha,  // [F]
    float* __restrict__ out)          // [N][F] in-place
{
  __shared__ float p_lds[16 * F];     // 8 KB
  const int t  = threadIdx.x;
  const int n0 = blockIdx.x * 16;

  // load 16 rows + PReLU -> LDS
  {
    const int lr = t >> 4, c8 = (t & 15) * 8;
    const float* ip = out + (size_t)(n0 + lr) * F + c8;
    f4 v0 = *(const f4*)(ip);
    f4 v1 = *(const f4*)(ip + 4);
    f4 a0 = *(const f4*)(alpha + c8);
    f4 a1 = *(const f4*)(alpha + c8 + 4);
#pragma unroll
    for (int j = 0; j < 4; ++j) {
      v0[j] = v0[j] >= 0.f ? v0[j] : a0[j] * v0[j];
      v1[j] = v1[j] >= 0.f ? v1[j] : a1[j] * v1[j];
    }
    *(f4*)&p_lds[lr * F + c8]     = v0;
    *(f4*)&p_lds[lr * F + c8 + 4] = v1;
  }
  __syncthreads();

  // FC: thread -> rows {r2, r2+8}, outputs fo0..fo0+3; W streamed from L2
  const int r2  = t >> 5;             // 0..7
  const int fo0 = (t & 31) * 4;
  f4 accA = *(const f4*)(bfc + fo0);
  f4 accB = accA;
#pragma unroll 4
  for (int fi4 = 0; fi4 < F / 4; ++fi4) {
    f4 pA = *(const f4*)&p_lds[r2 * F + fi4 * 4];
    f4 pB = *(const f4*)&p_lds[(r2 + 8) * F + fi4 * 4];
#pragma unroll
    for (int e = 0; e < 4; ++e) {
      f4 wv = *(const f4*)(W + (size_t)(fo0 + e) * F + fi4 * 4);
      accA[e] = fmaf(pA[0], wv[0], fmaf(pA[1], wv[1],
                fmaf(pA[2], wv[2], fmaf(pA[3], wv[3], accA[e]))));
      accB[e] = fmaf(pB[0], wv[0], fmaf(pB[1], wv[1],
                fmaf(pB[2], wv[2], fmaf(pB[3], wv[3], accB[e]))));
    }
  }
  *(f4*)(out + (size_t)(n0 + r2) * F + fo0)     = accA;
  *(f4*)(out + (size_t)(n0 + r2 + 8) * F + fo0) = accB;
}

extern "C" void kernel_launch(void* const* d_in, const int* in_sizes, int n_in,
                              void* d_out, int out_size, void* d_ws, size_t ws_size,
                              hipStream_t stream) {
  const float* theta = (const float*)d_in[0];
  const float* Ts    = (const float*)d_in[1];
  const float* x     = (const float*)d_in[2];
  const float* a     = (const float*)d_in[3];
  const float* W     = (const float*)d_in[4];
  const float* bfc   = (const float*)d_in[5];
  const float* alpha = (const float*)d_in[6];
  float* out = (float*)d_out;

  // zero the accumulator (graph-capturable)
  hipMemsetAsync(out, 0, (size_t)out_size * sizeof(float), stream);

  ggd_diffuse<<<dim3((N / BM) * KSPLIT), dim3(NT), 0, stream>>>(
      theta, Ts, x, a, out);

  ggd_fc<<<dim3(N / 16), dim3(256), 0, stream>>>(W, bfc, alpha, out);
}

// Round 5
// 171.256 us; speedup vs baseline: 10.5478x; 5.3809x over previous
//
#include <hip/hip_runtime.h>

// S=8, N=4096, F_IN=F_OUT=128
constexpr int N  = 4096;
constexpr int F  = 128;
constexpr int S  = 8;
constexpr int BM = 32;              // rows per block (kernel1)
constexpr int KSPLIT = 8;
constexpr int KRANGE = N / KSPLIT;  // 512
constexpr int BK = 32;              // k-chunk
constexpr int NCH = KRANGE / BK;    // 16 chunks per block
constexpr int NT = 256;

typedef float f4 __attribute__((ext_vector_type(4)));

// Barrier that waits only on LDS ops; global loads stay in flight unless we
// explicitly drain vmcnt first.
__device__ __forceinline__ void bar_sync() {
  asm volatile("s_waitcnt lgkmcnt(0)" ::: "memory");
  __builtin_amdgcn_s_barrier();
  asm volatile("" ::: "memory");
}

__device__ __forceinline__ void vm_drain() {
  asm volatile("s_waitcnt vmcnt(0)" ::: "memory");
}

// async global->LDS, 16B per lane; LDS dest = wave-uniform base + lane*16.
__device__ __forceinline__ void gload_lds16(const float* g, float* l) {
  __builtin_amdgcn_global_load_lds(
      (const __attribute__((address_space(1))) void*)g,
      (__attribute__((address_space(3))) void*)l, 16, 0, 0);
}

// ---------------- kernel 1: q-gen + q@x partial, k-split ----------------
__global__ __launch_bounds__(NT, 4) void ggd_diffuse(
    const float* __restrict__ theta,
    const float* __restrict__ Ts,     // [S][N][N]
    const float* __restrict__ x,      // [N][F]
    const float* __restrict__ a,      // [N][N]
    float* __restrict__ out)          // [N][F] accumulator (pre-zeroed)
{
  __shared__ float q_lds[2][BM][BK];  // 8 KB, double-buffered, linear
  __shared__ float x_lds[2][BK * F];  // 32 KB, double-buffered, linear

  const int t  = threadIdx.x;
  const int rb = blockIdx.x >> 3;     // 0..127  row block
  const int ks = blockIdx.x & 7;      // 0..7    k-split (~1:1 with XCD)
  const int n0 = rb * BM;
  const int k0 = ks * KRANGE;

  float th[S];
#pragma unroll
  for (int s = 0; s < S; ++s) th[s] = theta[s];

  const int wave = t >> 6, lane = t & 63;

  // producer mapping: ONE f4 per thread: row pr, cols pk..pk+3
  // wave writes q_lds linearly (lane*16B contiguous) -> conflict-free
  const int pr = t >> 3;              // 0..31
  const int pk = (t & 7) * 4;         // 0,4,...,28
  const size_t prowOff = (size_t)(n0 + pr) * N + k0 + pk;
  const size_t slice   = (size_t)N * N;

  // consumer mapping: rows rg*4..rg*4+3, feats fg*4..fg*4+3
  const int rg = t >> 5;              // 0..7
  const int fg = t & 31;              // 0..31

  f4 acc[4];
#pragma unroll
  for (int r = 0; r < 4; ++r) acc[r] = (f4)(0.f);

  // staging registers for next chunk's T/a: 9 f4 = 36 VGPR
  f4 sa;
  f4 st[S];

  auto load_Ta = [&](int c) {
    const size_t off = prowOff + (size_t)c * BK;
    sa = *(const f4*)(a + off);
#pragma unroll
    for (int s = 0; s < S; ++s)
      st[s] = *(const f4*)(Ts + (size_t)s * slice + off);
  };

  auto commit_q = [&](int buf) {
    f4 q;
#pragma unroll
    for (int j = 0; j < 4; ++j) {
      float sum = th[0] * st[0][j];
#pragma unroll
      for (int s = 1; s < S; ++s) sum = fmaf(th[s], st[s][j], sum);
      q[j] = sa[j] * sum;
    }
    *(f4*)&q_lds[buf][pr][pk] = q;
  };

  auto stage_x = [&](int c, int buf) {
    const float* xg = x + (size_t)(k0 + c * BK) * F;
#pragma unroll
    for (int i = 0; i < 4; ++i) {
      const int seg = (wave * 4 + i) * 256;   // wave-uniform LDS base
      gload_lds16(xg + seg + lane * 4, &x_lds[buf][seg]);
    }
  };

  // prologue
  load_Ta(0);
  stage_x(0, 0);
  commit_q(0);
  vm_drain();
  bar_sync();

  for (int c = 0; c < NCH; ++c) {
    const int buf = c & 1;
    if (c + 1 < NCH) {
      load_Ta(c + 1);             // 9 f4 -> regs; waited by commit_q below
      stage_x(c + 1, buf ^ 1);    // async -> LDS; waited by vm_drain below
    }

    // ---- compute chunk c purely from LDS ----
    const float* qb = &q_lds[buf][rg * 4][0];
    const float* xb = &x_lds[buf][0] + fg * 4;
#pragma unroll
    for (int k4 = 0; k4 < BK / 4; ++k4) {
      f4 xv[4];
#pragma unroll
      for (int j = 0; j < 4; ++j)
        xv[j] = *(const f4*)(xb + (size_t)(k4 * 4 + j) * F);
#pragma unroll
      for (int rr = 0; rr < 4; ++rr) {
        f4 qv = *(const f4*)(qb + rr * BK + k4 * 4);
#pragma unroll
        for (int j = 0; j < 4; ++j)
#pragma unroll
          for (int e = 0; e < 4; ++e)
            acc[rr][e] = fmaf(qv[j], xv[j][e], acc[rr][e]);
      }
    }

    if (c + 1 < NCH) commit_q(buf ^ 1);  // vmcnt wait for st/sa lands here
    vm_drain();                           // x[c+1] resident in LDS
    bar_sync();                           // publish q[c+1] + x[c+1]
  }

  // accumulate partials (8 k-split blocks contribute per row)
#pragma unroll
  for (int rr = 0; rr < 4; ++rr) {
    float* op = out + (size_t)(n0 + rg * 4 + rr) * F + fg * 4;
#pragma unroll
    for (int e = 0; e < 4; ++e) atomicAdd(op + e, acc[rr][e]);
  }
}

// ---------------- kernel 2: PReLU + FC, in-place on out ----------------
__global__ __launch_bounds__(256, 2) void ggd_fc(
    const float* __restrict__ W,      // [F][F] row-major [fo][fi]
    const float* __restrict__ bfc,    // [F]
    const float* __restrict__ alpha,  // [F]
    float* __restrict__ out)          // [N][F] in-place
{
  __shared__ float p_lds[16 * F];     // 8 KB
  const int t  = threadIdx.x;
  const int n0 = blockIdx.x * 16;

  // load 16 rows + PReLU -> LDS
  {
    const int lr = t >> 4, c8 = (t & 15) * 8;
    const float* ip = out + (size_t)(n0 + lr) * F + c8;
    f4 v0 = *(const f4*)(ip);
    f4 v1 = *(const f4*)(ip + 4);
    f4 a0 = *(const f4*)(alpha + c8);
    f4 a1 = *(const f4*)(alpha + c8 + 4);
#pragma unroll
    for (int j = 0; j < 4; ++j) {
      v0[j] = v0[j] >= 0.f ? v0[j] : a0[j] * v0[j];
      v1[j] = v1[j] >= 0.f ? v1[j] : a1[j] * v1[j];
    }
    *(f4*)&p_lds[lr * F + c8]     = v0;
    *(f4*)&p_lds[lr * F + c8 + 4] = v1;
  }
  __syncthreads();

  // FC: thread -> rows {r2, r2+8}, outputs fo0..fo0+3; W streamed from L2
  const int r2  = t >> 5;             // 0..7
  const int fo0 = (t & 31) * 4;
  f4 accA = *(const f4*)(bfc + fo0);
  f4 accB = accA;
#pragma unroll 4
  for (int fi4 = 0; fi4 < F / 4; ++fi4) {
    f4 pA = *(const f4*)&p_lds[r2 * F + fi4 * 4];
    f4 pB = *(const f4*)&p_lds[(r2 + 8) * F + fi4 * 4];
#pragma unroll
    for (int e = 0; e < 4; ++e) {
      f4 wv = *(const f4*)(W + (size_t)(fo0 + e) * F + fi4 * 4);
      accA[e] = fmaf(pA[0], wv[0], fmaf(pA[1], wv[1],
                fmaf(pA[2], wv[2], fmaf(pA[3], wv[3], accA[e]))));
      accB[e] = fmaf(pB[0], wv[0], fmaf(pB[1], wv[1],
                fmaf(pB[2], wv[2], fmaf(pB[3], wv[3], accB[e]))));
    }
  }
  *(f4*)(out + (size_t)(n0 + r2) * F + fo0)     = accA;
  *(f4*)(out + (size_t)(n0 + r2 + 8) * F + fo0) = accB;
}

extern "C" void kernel_launch(void* const* d_in, const int* in_sizes, int n_in,
                              void* d_out, int out_size, void* d_ws, size_t ws_size,
                              hipStream_t stream) {
  const float* theta = (const float*)d_in[0];
  const float* Ts    = (const float*)d_in[1];
  const float* x     = (const float*)d_in[2];
  const float* a     = (const float*)d_in[3];
  const float* W     = (const float*)d_in[4];
  const float* bfc   = (const float*)d_in[5];
  const float* alpha = (const float*)d_in[6];
  float* out = (float*)d_out;

  // zero the accumulator (graph-capturable)
  hipMemsetAsync(out, 0, (size_t)out_size * sizeof(float), stream);

  ggd_diffuse<<<dim3((N / BM) * KSPLIT), dim3(NT), 0, stream>>>(
      theta, Ts, x, a, out);

  ggd_fc<<<dim3(N / 16), dim3(256), 0, stream>>>(W, bfc, alpha, out);
}